// Round 1
// baseline (771.872 us; speedup 1.0000x reference)
//
#include <hip/hip_runtime.h>
#include <hip/hip_bf16.h>

typedef _Float16 f16x8 __attribute__((ext_vector_type(8)));
typedef float    f32x4 __attribute__((ext_vector_type(4)));

#define T_STEPS 1024
#define BATCH   128
#define DH      256   // hidden == input dim == 256

// ---------------------------------------------------------------------------
// Kernel 1: xp[t,b,:] = x[t,b,:] @ W_ih^T + b_ih + b_hh   (written into d_out)
// f16 hi/lo split (3 MFMA passes) => ~fp32 accuracy at f16-MFMA rate.
// Tiles: BM=128 (over M=T*B), BN=128 (N=256 -> 2 col-blocks), BK=64.
// LDS 64KB -> 2 blocks/CU. XOR-swizzled LDS (G4) for conflict-free ds_read_b128.
// ---------------------------------------------------------------------------
#define BM 128
#define BN 128
#define BK 64

__device__ __forceinline__ void stage_tile(const float* __restrict__ src,
                                           int row0, int kc,
                                           unsigned short* hi, unsigned short* lo,
                                           int t) {
  // 128 rows x 64 cols f32 = 2048 float4; 256 threads x 8 each. Coalesced.
#pragma unroll
  for (int i = 0; i < 8; ++i) {
    int f   = i * 256 + t;      // float4 slot 0..2047
    int row = f >> 4;           // 16 float4 per row
    int q   = f & 15;
    const float4 v = *(const float4*)&src[(size_t)(row0 + row) * 256 + kc + q * 4];
    _Float16 h0 = (_Float16)v.x, h1 = (_Float16)v.y,
             h2 = (_Float16)v.z, h3 = (_Float16)v.w;
    _Float16 l0 = (_Float16)(v.x - (float)h0), l1 = (_Float16)(v.y - (float)h1),
             l2 = (_Float16)(v.z - (float)h2), l3 = (_Float16)(v.w - (float)h3);
    // bf16 row = 64 elems * 2B = 128B; swizzle 16B blocks by row&7 (G4).
    unsigned int off = (unsigned int)(row * 128 + q * 8) ^ ((row & 7) << 4);
    union { _Float16 h[4]; uint2 u; } ph, pl;
    ph.h[0] = h0; ph.h[1] = h1; ph.h[2] = h2; ph.h[3] = h3;
    pl.h[0] = l0; pl.h[1] = l1; pl.h[2] = l2; pl.h[3] = l3;
    *(uint2*)((char*)hi + off) = ph.u;
    *(uint2*)((char*)lo + off) = pl.u;
  }
}

__global__ __launch_bounds__(256, 2) void xp_gemm(
    const float* __restrict__ x,   const float* __restrict__ Wih,
    const float* __restrict__ bih, const float* __restrict__ bhh,
    float* __restrict__ out) {
  __shared__ __align__(16) unsigned short Ah[BM * BK], Al[BM * BK];
  __shared__ __align__(16) unsigned short Bh[BN * BK], Bl[BN * BK];
  const int t    = threadIdx.x;
  const int m0   = blockIdx.x * BM;      // over M = T*B
  const int n0   = blockIdx.y * BN;      // 0 or 128
  const int lane = t & 63;
  const int wave = t >> 6;
  const int wm = wave >> 1, wn = wave & 1;   // 2x2 waves, 64x64 each

  f32x4 acc[4][4];
#pragma unroll
  for (int i = 0; i < 4; ++i)
#pragma unroll
    for (int j = 0; j < 4; ++j) acc[i][j] = (f32x4)0.0f;

  for (int kc = 0; kc < 256; kc += BK) {
    stage_tile(x,   m0, kc, Ah, Al, t);
    stage_tile(Wih, n0, kc, Bh, Bl, t);
    __syncthreads();
#pragma unroll
    for (int ks = 0; ks < 2; ++ks) {     // two K=32 steps per chunk
      f16x8 ah[4], al[4], bh[4], bl[4];
#pragma unroll
      for (int mi = 0; mi < 4; ++mi) {
        int row = wm * 64 + mi * 16 + (lane & 15);
        unsigned int off =
            (unsigned int)(row * 128 + ks * 64 + ((lane >> 4) << 4)) ^ ((row & 7) << 4);
        ah[mi] = *(const f16x8*)((const char*)Ah + off);
        al[mi] = *(const f16x8*)((const char*)Al + off);
      }
#pragma unroll
      for (int ni = 0; ni < 4; ++ni) {
        int row = wn * 64 + ni * 16 + (lane & 15);
        unsigned int off =
            (unsigned int)(row * 128 + ks * 64 + ((lane >> 4) << 4)) ^ ((row & 7) << 4);
        bh[ni] = *(const f16x8*)((const char*)Bh + off);
        bl[ni] = *(const f16x8*)((const char*)Bl + off);
      }
#pragma unroll
      for (int mi = 0; mi < 4; ++mi)
#pragma unroll
        for (int ni = 0; ni < 4; ++ni) {
          acc[mi][ni] = __builtin_amdgcn_mfma_f32_16x16x32_f16(ah[mi], bh[ni], acc[mi][ni], 0, 0, 0);
          acc[mi][ni] = __builtin_amdgcn_mfma_f32_16x16x32_f16(ah[mi], bl[ni], acc[mi][ni], 0, 0, 0);
          acc[mi][ni] = __builtin_amdgcn_mfma_f32_16x16x32_f16(al[mi], bh[ni], acc[mi][ni], 0, 0, 0);
        }
    }
    __syncthreads();
  }
  // epilogue: + (b_ih + b_hh), store fp32. C/D layout: col=lane&15, row=(lane>>4)*4+r
#pragma unroll
  for (int ni = 0; ni < 4; ++ni) {
    int col = n0 + wn * 64 + ni * 16 + (lane & 15);
    float bias = bih[col] + bhh[col];
#pragma unroll
    for (int mi = 0; mi < 4; ++mi) {
      int rbase = m0 + wm * 64 + mi * 16 + ((lane >> 4) << 2);
#pragma unroll
      for (int r = 0; r < 4; ++r)
        out[(size_t)(rbase + r) * DH + col] = acc[mi][ni][r] + bias;
    }
  }
}

// ---------------------------------------------------------------------------
// Kernel 2: the recurrence. One WG per batch element (128 WGs, zero inter-WG
// communication). 512 threads: thread owns 4 output features (j0..j0+3) and a
// 32-wide k-slice; W_hh slice lives in 128 VGPRs for the whole kernel.
// Per step: FMA phase (h broadcast via same-address float4 LDS reads) ->
// partials to LDS -> 256 threads reduce + xp + tanh -> h to LDS + out.
// xp is read from d_out and overwritten in place with h (same layout).
// ---------------------------------------------------------------------------
__global__ __launch_bounds__(512, 2) void rnn_rec(
    const float* __restrict__ Whh, float* __restrict__ xh) {
  const int b  = blockIdx.x;
  const int t  = threadIdx.x;
  const int j0 = (t & 63) << 2;   // 4 consecutive output features
  const int kg = t >> 6;          // k-group 0..7 (32 k each)

  __shared__ float hs[DH];
  __shared__ float part[8][DH];

  // W_hh[j0+i][kg*32 .. +31] -> registers (fully static indexing after unroll)
  float w[4][32];
#pragma unroll
  for (int i = 0; i < 4; ++i)
#pragma unroll
    for (int q = 0; q < 8; ++q)
      *(float4*)&w[i][q * 4] =
          *(const float4*)&Whh[(size_t)(j0 + i) * DH + kg * 32 + q * 4];

  if (t < DH) hs[t] = 0.0f;   // h0 = 0
  __syncthreads();

  float* base = xh + (size_t)b * DH;
  for (int s = 0; s < T_STEPS; ++s) {
    // prefetch xp for this step (waves 0-3); hides HBM latency under FMA phase
    float xpv = 0.0f;
    if (t < DH) xpv = base[(size_t)s * (BATCH * DH) + t];

    float a0 = 0.f, a1 = 0.f, a2 = 0.f, a3 = 0.f;
    const float* hp = &hs[kg * 32];
#pragma unroll
    for (int q = 0; q < 8; ++q) {
      float4 hv = *(const float4*)(hp + q * 4);   // same addr across wave: broadcast
      a0 = fmaf(w[0][q*4+0], hv.x, a0); a0 = fmaf(w[0][q*4+1], hv.y, a0);
      a0 = fmaf(w[0][q*4+2], hv.z, a0); a0 = fmaf(w[0][q*4+3], hv.w, a0);
      a1 = fmaf(w[1][q*4+0], hv.x, a1); a1 = fmaf(w[1][q*4+1], hv.y, a1);
      a1 = fmaf(w[1][q*4+2], hv.z, a1); a1 = fmaf(w[1][q*4+3], hv.w, a1);
      a2 = fmaf(w[2][q*4+0], hv.x, a2); a2 = fmaf(w[2][q*4+1], hv.y, a2);
      a2 = fmaf(w[2][q*4+2], hv.z, a2); a2 = fmaf(w[2][q*4+3], hv.w, a2);
      a3 = fmaf(w[3][q*4+0], hv.x, a3); a3 = fmaf(w[3][q*4+1], hv.y, a3);
      a3 = fmaf(w[3][q*4+2], hv.z, a3); a3 = fmaf(w[3][q*4+3], hv.w, a3);
    }
    *(float4*)&part[kg][j0] = make_float4(a0, a1, a2, a3);
    __syncthreads();

    if (t < DH) {
      float v = xpv;
#pragma unroll
      for (int g = 0; g < 8; ++g) v += part[g][t];
      float h = tanhf(v);
      hs[t] = h;
      base[(size_t)s * (BATCH * DH) + t] = h;   // overwrite xp with h in place
    }
    __syncthreads();
  }
}

extern "C" void kernel_launch(void* const* d_in, const int* in_sizes, int n_in,
                              void* d_out, int out_size, void* d_ws, size_t ws_size,
                              hipStream_t stream) {
  const float* x   = (const float*)d_in[0];
  const float* Wih = (const float*)d_in[1];
  const float* Whh = (const float*)d_in[2];
  const float* bih = (const float*)d_in[3];
  const float* bhh = (const float*)d_in[4];
  float* out = (float*)d_out;

  dim3 g1((T_STEPS * BATCH) / BM, DH / BN);   // 1024 x 2
  xp_gemm<<<g1, dim3(256), 0, stream>>>(x, Wih, bih, bhh, out);
  rnn_rec<<<BATCH, dim3(512), 0, stream>>>(Whh, out);
}